// Round 10
// baseline (127.157 us; speedup 1.0000x reference)
//
#include <hip/hip_runtime.h>
#include <hip/hip_bf16.h>

#define B_ 8
#define N_ 512
#define F_ 128
#define H_ 4
#define U_ 32
#define LEAKY_ALPHA 0.2f
#define PS 520     // pbf row stride (bf16 elems)

typedef __attribute__((ext_vector_type(8))) short short8;
typedef __attribute__((ext_vector_type(4))) float f32x4;

static __device__ __forceinline__ short f2bf_s(float x) {
    __hip_bfloat16 hv = __float2bfloat16(x);
    return *reinterpret_cast<short*>(&hv);
}
static __device__ __forceinline__ float bf2f_s(short v) {
    return __uint_as_float(((unsigned)(unsigned short)v) << 16);
}

#define PINF4(v) asm volatile("" : "+v"(v.x), "+v"(v.y), "+v"(v.z), "+v"(v.w))

// ---------------------------------------------------------------------------
// Kernel 1: projections — NO LDS. x rows are block-uniform; loaded via a
// manually software-pipelined ping-pong (pinned float4 batches) so the
// scalar/vector load latency for batch k+1 hides under batch k's 64 FMAs.
//   hsrc   = x@Wsrc (f32)           [bh][n][u]
//   hsrcT  = bf16(x@Wsrc)^T         [bh*32+u][n]  (MFMA B-frag layout)
//   hdstNT = -(x@Wdst) (f32)^T      [bh*32+u][j]  (coalesced per-lane d-rows)
//   Drow[j] = sum_u a_u d_ju ; ascaled = 0.8*a
// ---------------------------------------------------------------------------
__global__ __launch_bounds__(256) void proj_kernel(
    const float* __restrict__ x, const float* __restrict__ Wsrc,
    const float* __restrict__ Wdst, const float* __restrict__ a,
    float* __restrict__ hsrc, float* __restrict__ hdstNT,
    float* __restrict__ Drow, float* __restrict__ ascaled,
    short* __restrict__ hsrcT)
{
    const int t  = threadIdx.x;
    const int r0 = blockIdx.x * 8;

    const int u     = t & 31;
    const int h     = (t >> 5) & 3;
    const int which = t >> 7;
    const float* W  = (which ? Wdst : Wsrc) + h * (F_ * U_) + u;
    const float* xrow = x + (size_t)r0 * F_;

    float acc[8];
#pragma unroll
    for (int r = 0; r < 8; ++r) acc[r] = 0.f;

    float4 xa[8], xb[8];
#define LDX(buf, fc)                                                        \
    {                                                                       \
        _Pragma("unroll")                                                   \
        for (int r = 0; r < 8; ++r)                                         \
            buf[r] = *(const float4*)(xrow + r * F_ + (fc) * 4);            \
        _Pragma("unroll")                                                   \
        for (int r = 0; r < 8; ++r) PINF4(buf[r]);                          \
    }
#define CMP(buf, fc)                                                        \
    {                                                                       \
        const float w0 = W[(4 * (fc) + 0) * U_];                            \
        const float w1 = W[(4 * (fc) + 1) * U_];                            \
        const float w2 = W[(4 * (fc) + 2) * U_];                            \
        const float w3 = W[(4 * (fc) + 3) * U_];                            \
        _Pragma("unroll")                                                   \
        for (int r = 0; r < 8; ++r) {                                       \
            float s = acc[r];                                               \
            s = fmaf(buf[r].x, w0, s);                                      \
            s = fmaf(buf[r].y, w1, s);                                      \
            s = fmaf(buf[r].z, w2, s);                                      \
            s = fmaf(buf[r].w, w3, s);                                      \
            acc[r] = s;                                                     \
        }                                                                   \
    }

    LDX(xa, 0)
    for (int fc = 0; fc < 32; fc += 2) {
        LDX(xb, fc + 1)
        CMP(xa, fc)
        if (fc + 2 < 32) LDX(xa, fc + 2)
        CMP(xb, fc + 1)
    }
#undef LDX
#undef CMP

    const float av = a[h * U_ + u];
    if (which == 1 && blockIdx.x == 0)
        ascaled[h * U_ + u] = (1.f - LEAKY_ALPHA) * av;

    const int b  = r0 >> 9;
    const int n0 = r0 & (N_ - 1);
    const int bh = b * H_ + h;

    if (which == 0) {
        short8 pk;
#pragma unroll
        for (int r = 0; r < 8; ++r) {
            const size_t base = ((size_t)(bh * N_ + n0 + r) << 5) + u;
            hsrc[base] = acc[r];
            pk[r] = f2bf_s(acc[r]);
        }
        *(short8*)&hsrcT[((size_t)(bh * U_) + u) * N_ + n0] = pk;
    } else {
        float4 v0, v1;
        v0.x = -acc[0]; v0.y = -acc[1]; v0.z = -acc[2]; v0.w = -acc[3];
        v1.x = -acc[4]; v1.y = -acc[5]; v1.z = -acc[6]; v1.w = -acc[7];
        float* dst = hdstNT + ((size_t)(bh * U_) + u) * N_ + n0;
        *(float4*)dst       = v0;
        *(float4*)(dst + 4) = v1;
#pragma unroll
        for (int r = 0; r < 8; ++r) {
            float v = acc[r] * av;
            v += __shfl_xor(v, 1);
            v += __shfl_xor(v, 2);
            v += __shfl_xor(v, 4);
            v += __shfl_xor(v, 8);
            v += __shfl_xor(v, 16);
            if (u == 0) Drow[bh * N_ + n0 + r] = v;
        }
    }
}

// ---------------------------------------------------------------------------
// Kernel 2: attention. Block = 512 thr = 8 waves; lane = j owns one d-row
// (32 pinned scalars, coalesced from hdstNT). s-rows are block-uniform and
// fetched via a pinned ping-pong (2 x 8 float4): the lgkmcnt/vmcnt wait for
// row i+1 lands AFTER row i's 64 VALU ops -> latency hidden regardless of
// how the compiler schedules. Phase A: zero LDS reads, zero shuffles.
// l computed by an all-thread pbf reduce; Phase C: MFMA p @ srcT (R7 path).
// Grid = 32 bh x 32 tiles(16 i) = 1024 blocks.
// ---------------------------------------------------------------------------
__global__ __launch_bounds__(512, 4) void attn_kernel(
    const float* __restrict__ hsrc, const float* __restrict__ hdstNT,
    const float* __restrict__ Drow, const float* __restrict__ ascaled,
    const short* __restrict__ hsrcT, float* __restrict__ out)
{
    __shared__ __align__(16) short pbf[16 * PS];  // 16.6 KB p bf16 [i][j]
    __shared__ f32x4 scr[8][64];                  // 8 KB K-partials
    __shared__ float lfin[16];                    // 1/l per i

    const int t    = threadIdx.x;
    const int L    = t & 63;
    const int w    = __builtin_amdgcn_readfirstlane(t >> 6);
    const int tile = blockIdx.x & 31;
    const int bh   = blockIdx.x >> 5;
    const int h    = bh & 3;
    const int b    = bh >> 2;
    const size_t bhN = (size_t)bh * N_;
    const int ig0  = tile * 16;
    const int j    = t;                           // lane owns column j

    // ---- per-lane d-row (coalesced, pinned) ----
    const float* dT = hdstNT + ((size_t)bh * U_) * N_ + j;
#define DL(k) float d##k = dT[(k) * N_];
    DL(0) DL(1) DL(2) DL(3) DL(4) DL(5) DL(6) DL(7)
    DL(8) DL(9) DL(10) DL(11) DL(12) DL(13) DL(14) DL(15)
    DL(16) DL(17) DL(18) DL(19) DL(20) DL(21) DL(22) DL(23)
    DL(24) DL(25) DL(26) DL(27) DL(28) DL(29) DL(30) DL(31)
#undef DL
#define PIN4(a0,a1,a2,a3) asm volatile("" : "+v"(a0), "+v"(a1), "+v"(a2), "+v"(a3));
    PIN4(d0,d1,d2,d3)     PIN4(d4,d5,d6,d7)
    PIN4(d8,d9,d10,d11)   PIN4(d12,d13,d14,d15)
    PIN4(d16,d17,d18,d19) PIN4(d20,d21,d22,d23)
    PIN4(d24,d25,d26,d27) PIN4(d28,d29,d30,d31)
#undef PIN4

    const float Dj = Drow[bhN + j];
    const float* sBase = hsrc + ((bhN + ig0) << 5);   // 16x32, block-uniform
    const float* aS = ascaled + h * U_;               // block-uniform (SGPR)

    float4 sa[8], sb[8];
#define LDS_(buf, ii)                                                       \
    {                                                                       \
        const float4* _p = (const float4*)(sBase + ((ii) << 5));            \
        _Pragma("unroll")                                                   \
        for (int q = 0; q < 8; ++q) buf[q] = _p[q];                         \
        _Pragma("unroll")                                                   \
        for (int q = 0; q < 8; ++q) PINF4(buf[q]);                          \
    }
#define SCORE(buf, ii)                                                      \
    {                                                                       \
        float acA = 0.f, acB = 0.f;                                         \
        acA = fmaf(aS[0],  fmaxf(buf[0].x, d0 ), acA);                      \
        acB = fmaf(aS[1],  fmaxf(buf[0].y, d1 ), acB);                      \
        acA = fmaf(aS[2],  fmaxf(buf[0].z, d2 ), acA);                      \
        acB = fmaf(aS[3],  fmaxf(buf[0].w, d3 ), acB);                      \
        acA = fmaf(aS[4],  fmaxf(buf[1].x, d4 ), acA);                      \
        acB = fmaf(aS[5],  fmaxf(buf[1].y, d5 ), acB);                      \
        acA = fmaf(aS[6],  fmaxf(buf[1].z, d6 ), acA);                      \
        acB = fmaf(aS[7],  fmaxf(buf[1].w, d7 ), acB);                      \
        acA = fmaf(aS[8],  fmaxf(buf[2].x, d8 ), acA);                      \
        acB = fmaf(aS[9],  fmaxf(buf[2].y, d9 ), acB);                      \
        acA = fmaf(aS[10], fmaxf(buf[2].z, d10), acA);                      \
        acB = fmaf(aS[11], fmaxf(buf[2].w, d11), acB);                      \
        acA = fmaf(aS[12], fmaxf(buf[3].x, d12), acA);                      \
        acB = fmaf(aS[13], fmaxf(buf[3].y, d13), acB);                      \
        acA = fmaf(aS[14], fmaxf(buf[3].z, d14), acA);                      \
        acB = fmaf(aS[15], fmaxf(buf[3].w, d15), acB);                      \
        acA = fmaf(aS[16], fmaxf(buf[4].x, d16), acA);                      \
        acB = fmaf(aS[17], fmaxf(buf[4].y, d17), acB);                      \
        acA = fmaf(aS[18], fmaxf(buf[4].z, d18), acA);                      \
        acB = fmaf(aS[19], fmaxf(buf[4].w, d19), acB);                      \
        acA = fmaf(aS[20], fmaxf(buf[5].x, d20), acA);                      \
        acB = fmaf(aS[21], fmaxf(buf[5].y, d21), acB);                      \
        acA = fmaf(aS[22], fmaxf(buf[5].z, d22), acA);                      \
        acB = fmaf(aS[23], fmaxf(buf[5].w, d23), acB);                      \
        acA = fmaf(aS[24], fmaxf(buf[6].x, d24), acA);                      \
        acB = fmaf(aS[25], fmaxf(buf[6].y, d25), acB);                      \
        acA = fmaf(aS[26], fmaxf(buf[6].z, d26), acA);                      \
        acB = fmaf(aS[27], fmaxf(buf[6].w, d27), acB);                      \
        acA = fmaf(aS[28], fmaxf(buf[7].x, d28), acA);                      \
        acB = fmaf(aS[29], fmaxf(buf[7].y, d29), acB);                      \
        acA = fmaf(aS[30], fmaxf(buf[7].z, d30), acA);                      \
        acB = fmaf(aS[31], fmaxf(buf[7].w, d31), acB);                      \
        const float e = __expf(Dj + acA + acB);                             \
        pbf[(ii) * PS + j] = f2bf_s(e);                                     \
    }

    LDS_(sa, 0)
    for (int i = 0; i < 16; i += 2) {
        LDS_(sb, i + 1)
        SCORE(sa, i)
        if (i + 2 < 16) LDS_(sa, i + 2)
        SCORE(sb, i + 1)
    }
#undef LDS_
#undef SCORE
    __syncthreads();

    // ---- l reduce: thread (ri = t>>5, rg = t&31) sums 16 j's of row ri ----
    {
        const int ri = t >> 5;
        const int rg = t & 31;
        const short8* pr = (const short8*)(pbf + ri * PS + rg * 16);
        const short8 pa = pr[0];
        const short8 pb = pr[1];
        float sum = 0.f;
#pragma unroll
        for (int k = 0; k < 8; ++k) sum += bf2f_s(pa[k]) + bf2f_s(pb[k]);
        sum += __shfl_xor(sum, 1);
        sum += __shfl_xor(sum, 2);
        sum += __shfl_xor(sum, 4);
        sum += __shfl_xor(sum, 8);
        sum += __shfl_xor(sum, 16);
        if (rg == 0) lfin[ri] = __builtin_amdgcn_rcpf(sum);
    }

    // ---- Phase C: MFMA  out = p @ src ; wave w = (nt = w&1, ks = w>>1) ----
    const int m  = L & 15;
    const int kq = L >> 4;
    const int nt = w & 1;
    const int ks = w >> 1;
    const short* Ap = pbf + m * PS + ks * 128 + kq * 8;
    const short* Bp = hsrcT + ((size_t)bh * U_ + nt * 16 + m) * N_ + ks * 128 + kq * 8;

    f32x4 acc = {0.f, 0.f, 0.f, 0.f};
#pragma unroll
    for (int st = 0; st < 4; ++st) {
        const short8 af = *(const short8*)(Ap + st * 32);
        const short8 bf = *(const short8*)(Bp + st * 32);
        acc = __builtin_amdgcn_mfma_f32_16x16x32_bf16(af, bf, acc, 0, 0, 0);
    }
    scr[w][L] = acc;
    __syncthreads();

    if (w < 2) {                               // wave w reduces ntile=w
        f32x4 s0 = scr[w][L];
        const f32x4 s1 = scr[w + 2][L];
        const f32x4 s2 = scr[w + 4][L];
        const f32x4 s3 = scr[w + 6][L];
        s0 += s1; s0 += s2; s0 += s3;
#pragma unroll
        for (int r = 0; r < 4; ++r) {
            const int il = kq * 4 + r;         // C/D: row=(lane>>4)*4+reg
            out[((size_t)(b * N_ + ig0 + il)) * (H_ * U_) + h * U_ + w * 16 + m]
                = s0[r] * lfin[il];
        }
    }
}

// ---------------------------------------------------------------------------
extern "C" void kernel_launch(void* const* d_in, const int* in_sizes, int n_in,
                              void* d_out, int out_size, void* d_ws, size_t ws_size,
                              hipStream_t stream) {
    const float* x    = (const float*)d_in[0];
    const float* Wsrc = (const float*)d_in[1];
    const float* Wdst = (const float*)d_in[2];
    const float* a    = (const float*)d_in[3];

    float* ws      = (float*)d_ws;
    float* hsrc    = ws;                                   // 524288 f
    float* hdstNT  = hsrc + (size_t)B_ * H_ * N_ * U_;     // 524288 f
    float* Drow    = hdstNT + (size_t)B_ * H_ * U_ * N_;   // 16384 f
    float* ascaled = Drow + (size_t)B_ * H_ * N_;          // 128 f
    short* hsrcT   = (short*)(ascaled + H_ * U_);          // 524288 sh

    proj_kernel<<<(B_ * N_) / 8, 256, 0, stream>>>(x, Wsrc, Wdst, a,
                                                   hsrc, hdstNT, Drow, ascaled,
                                                   hsrcT);
    attn_kernel<<<B_ * H_ * (N_ / 16), 512, 0, stream>>>(hsrc, hdstNT, Drow,
                                                         ascaled, hsrcT,
                                                         (float*)d_out);
}

// Round 11
// 109.541 us; speedup vs baseline: 1.1608x; 1.1608x over previous
//
#include <hip/hip_runtime.h>
#include <hip/hip_bf16.h>

#define B_ 8
#define N_ 512
#define F_ 128
#define H_ 4
#define U_ 32
#define LEAKY_ALPHA 0.2f
#define PS 520     // pbf row stride (bf16 elems)

typedef __attribute__((ext_vector_type(8))) short short8;
typedef __attribute__((ext_vector_type(4))) float f32x4;

static __device__ __forceinline__ short f2bf_s(float x) {
    __hip_bfloat16 hv = __float2bfloat16(x);
    return *reinterpret_cast<short*>(&hv);
}
static __device__ __forceinline__ float bf2f_s(short v) {
    return __uint_as_float(((unsigned)(unsigned short)v) << 16);
}

// ---------------------------------------------------------------------------
// Kernel 1: projections — NO LDS, NO pins. x rows are block-uniform and
// indexed directly -> the compiler scalarizes them to s_load (SGPR operands,
// zero VGPR pressure, zero LDS-pipe traffic — R8/R9's LDS version spent
// ~10 us on 256 broadcast ds_read_b128/thread). W loads are per-lane
// coalesced vector loads. fma = (SGPR x, VGPR w) -> legal 1-SGPR form.
//   hsrc   = x@Wsrc (f32)           [bh][n][u]
//   hsrcT  = bf16(x@Wsrc)^T         [bh*32+u][n]  (MFMA B-frag layout)
//   hdstNT = -(x@Wdst) (f32)^T      [bh*32+u][j]  (coalesced per-lane d-rows)
//   Drow[j] = sum_u a_u d_ju ; ascaled = 0.8*a
// score(i,j) ~ D_j + sum_u (0.8 a_u) max(s_iu, -d_ju)  (0.2*A_i dropped;
// softmax shift-invariant).
// ---------------------------------------------------------------------------
__global__ __launch_bounds__(256) void proj_kernel(
    const float* __restrict__ x, const float* __restrict__ Wsrc,
    const float* __restrict__ Wdst, const float* __restrict__ a,
    float* __restrict__ hsrc, float* __restrict__ hdstNT,
    float* __restrict__ Drow, float* __restrict__ ascaled,
    short* __restrict__ hsrcT)
{
    const int t  = threadIdx.x;
    const int r0 = blockIdx.x * 8;

    const int u     = t & 31;
    const int h     = (t >> 5) & 3;
    const int which = t >> 7;
    const float* W    = (which ? Wdst : Wsrc) + h * (F_ * U_) + u;
    const float* xrow = x + (size_t)r0 * F_;      // block-uniform base

    float acc[8];
#pragma unroll
    for (int r = 0; r < 8; ++r) acc[r] = 0.f;

#pragma unroll 4
    for (int fc = 0; fc < 32; ++fc) {
        const float w0 = W[(4 * fc + 0) * U_];    // per-lane, coalesced
        const float w1 = W[(4 * fc + 1) * U_];
        const float w2 = W[(4 * fc + 2) * U_];
        const float w3 = W[(4 * fc + 3) * U_];
#pragma unroll
        for (int r = 0; r < 8; ++r) {
            const float* xr = xrow + r * F_ + 4 * fc;   // uniform -> s_load
            float s = acc[r];
            s = fmaf(xr[0], w0, s);
            s = fmaf(xr[1], w1, s);
            s = fmaf(xr[2], w2, s);
            s = fmaf(xr[3], w3, s);
            acc[r] = s;
        }
    }

    const float av = a[h * U_ + u];
    if (which == 1 && blockIdx.x == 0)
        ascaled[h * U_ + u] = (1.f - LEAKY_ALPHA) * av;

    const int b  = r0 >> 9;
    const int n0 = r0 & (N_ - 1);
    const int bh = b * H_ + h;

    if (which == 0) {
        short8 pk;
#pragma unroll
        for (int r = 0; r < 8; ++r) {
            const size_t base = ((size_t)(bh * N_ + n0 + r) << 5) + u;
            hsrc[base] = acc[r];
            pk[r] = f2bf_s(acc[r]);
        }
        *(short8*)&hsrcT[((size_t)(bh * U_) + u) * N_ + n0] = pk;
    } else {
        float4 v0, v1;
        v0.x = -acc[0]; v0.y = -acc[1]; v0.z = -acc[2]; v0.w = -acc[3];
        v1.x = -acc[4]; v1.y = -acc[5]; v1.z = -acc[6]; v1.w = -acc[7];
        float* dst = hdstNT + ((size_t)(bh * U_) + u) * N_ + n0;
        *(float4*)dst       = v0;
        *(float4*)(dst + 4) = v1;
#pragma unroll
        for (int r = 0; r < 8; ++r) {
            float v = acc[r] * av;
            v += __shfl_xor(v, 1);
            v += __shfl_xor(v, 2);
            v += __shfl_xor(v, 4);
            v += __shfl_xor(v, 8);
            v += __shfl_xor(v, 16);
            if (u == 0) Drow[bh * N_ + n0 + r] = v;
        }
    }
}

// ---------------------------------------------------------------------------
// Kernel 2: attention — byte-identical to R9 (best measured: ~30 us).
// Block = 512 thr = 8 waves; lane = j owns one d-row (32 PINNED scalars,
// coalesced from hdstNT; live set ~50 regs, fits the 128 cap — no spill).
// s-rows and a are block-uniform -> scalar loads. Phase A: zero LDS reads,
// zero shuffles. l via all-thread pbf reduce; Phase C: MFMA p @ srcT.
// Grid = 32 bh x 32 tiles(16 i) = 1024 blocks.
// ---------------------------------------------------------------------------
__global__ __launch_bounds__(512, 4) void attn_kernel(
    const float* __restrict__ hsrc, const float* __restrict__ hdstNT,
    const float* __restrict__ Drow, const float* __restrict__ ascaled,
    const short* __restrict__ hsrcT, float* __restrict__ out)
{
    __shared__ __align__(16) short pbf[16 * PS];  // 16.6 KB p bf16 [i][j]
    __shared__ f32x4 scr[8][64];                  // 8 KB K-partials
    __shared__ float lfin[16];                    // 1/l per i

    const int t    = threadIdx.x;
    const int L    = t & 63;
    const int w    = __builtin_amdgcn_readfirstlane(t >> 6);
    const int tile = blockIdx.x & 31;
    const int bh   = blockIdx.x >> 5;
    const int h    = bh & 3;
    const int b    = bh >> 2;
    const size_t bhN = (size_t)bh * N_;
    const int ig0  = tile * 16;
    const int j    = t;                           // lane owns column j

    // ---- per-lane d-row (coalesced, pinned) ----
    const float* dT = hdstNT + ((size_t)bh * U_) * N_ + j;
#define DL(k) float d##k = dT[(k) * N_];
    DL(0) DL(1) DL(2) DL(3) DL(4) DL(5) DL(6) DL(7)
    DL(8) DL(9) DL(10) DL(11) DL(12) DL(13) DL(14) DL(15)
    DL(16) DL(17) DL(18) DL(19) DL(20) DL(21) DL(22) DL(23)
    DL(24) DL(25) DL(26) DL(27) DL(28) DL(29) DL(30) DL(31)
#undef DL
#define PIN4(a0,a1,a2,a3) asm volatile("" : "+v"(a0), "+v"(a1), "+v"(a2), "+v"(a3));
    PIN4(d0,d1,d2,d3)     PIN4(d4,d5,d6,d7)
    PIN4(d8,d9,d10,d11)   PIN4(d12,d13,d14,d15)
    PIN4(d16,d17,d18,d19) PIN4(d20,d21,d22,d23)
    PIN4(d24,d25,d26,d27) PIN4(d28,d29,d30,d31)
#undef PIN4

    const float Dj = Drow[bhN + j];
    const float* sB = hsrc + ((bhN + ig0) << 5);  // 16x32, block-uniform
    const float* aS = ascaled + h * U_;           // block-uniform

#define TERM(k, dk, accv) accv = fmaf(aS[k], fmaxf(sR[k], dk), accv);
#pragma unroll 2
    for (int i = 0; i < 16; ++i) {
        const float* sR = sB + (i << 5);          // uniform -> s_load
        float acA = 0.f, acB = 0.f;
        TERM(0,  d0,  acA) TERM(1,  d1,  acB) TERM(2,  d2,  acA) TERM(3,  d3,  acB)
        TERM(4,  d4,  acA) TERM(5,  d5,  acB) TERM(6,  d6,  acA) TERM(7,  d7,  acB)
        TERM(8,  d8,  acA) TERM(9,  d9,  acB) TERM(10, d10, acA) TERM(11, d11, acB)
        TERM(12, d12, acA) TERM(13, d13, acB) TERM(14, d14, acA) TERM(15, d15, acB)
        TERM(16, d16, acA) TERM(17, d17, acB) TERM(18, d18, acA) TERM(19, d19, acB)
        TERM(20, d20, acA) TERM(21, d21, acB) TERM(22, d22, acA) TERM(23, d23, acB)
        TERM(24, d24, acA) TERM(25, d25, acB) TERM(26, d26, acA) TERM(27, d27, acB)
        TERM(28, d28, acA) TERM(29, d29, acB) TERM(30, d30, acA) TERM(31, d31, acB)
        const float e = __expf(Dj + acA + acB);
        pbf[i * PS + j] = f2bf_s(e);
    }
#undef TERM
    __syncthreads();

    // ---- l reduce: thread (ri = t>>5, rg = t&31) sums 16 j's of row ri ----
    {
        const int ri = t >> 5;
        const int rg = t & 31;
        const short8* pr = (const short8*)(pbf + ri * PS + rg * 16);
        const short8 pa = pr[0];
        const short8 pb = pr[1];
        float sum = 0.f;
#pragma unroll
        for (int k = 0; k < 8; ++k) sum += bf2f_s(pa[k]) + bf2f_s(pb[k]);
        sum += __shfl_xor(sum, 1);
        sum += __shfl_xor(sum, 2);
        sum += __shfl_xor(sum, 4);
        sum += __shfl_xor(sum, 8);
        sum += __shfl_xor(sum, 16);
        if (rg == 0) lfin[ri] = __builtin_amdgcn_rcpf(sum);
    }

    // ---- Phase C: MFMA  out = p @ src ; wave w = (nt = w&1, ks = w>>1) ----
    const int m  = L & 15;
    const int kq = L >> 4;
    const int nt = w & 1;
    const int ks = w >> 1;
    const short* Ap = pbf + m * PS + ks * 128 + kq * 8;
    const short* Bp = hsrcT + ((size_t)bh * U_ + nt * 16 + m) * N_ + ks * 128 + kq * 8;

    f32x4 acc = {0.f, 0.f, 0.f, 0.f};
#pragma unroll
    for (int st = 0; st < 4; ++st) {
        const short8 af = *(const short8*)(Ap + st * 32);
        const short8 bf = *(const short8*)(Bp + st * 32);
        acc = __builtin_amdgcn_mfma_f32_16x16x32_bf16(af, bf, acc, 0, 0, 0);
    }
    scr[w][L] = acc;
    __syncthreads();

    if (w < 2) {                               // wave w reduces ntile=w
        f32x4 s0 = scr[w][L];
        const f32x4 s1 = scr[w + 2][L];
        const f32x4 s2 = scr[w + 4][L];
        const f32x4 s3 = scr[w + 6][L];
        s0 += s1; s0 += s2; s0 += s3;
#pragma unroll
        for (int r = 0; r < 4; ++r) {
            const int il = kq * 4 + r;         // C/D: row=(lane>>4)*4+reg
            out[((size_t)(b * N_ + ig0 + il)) * (H_ * U_) + h * U_ + w * 16 + m]
                = s0[r] * lfin[il];
        }
    }
}

// ---------------------------------------------------------------------------
extern "C" void kernel_launch(void* const* d_in, const int* in_sizes, int n_in,
                              void* d_out, int out_size, void* d_ws, size_t ws_size,
                              hipStream_t stream) {
    const float* x    = (const float*)d_in[0];
    const float* Wsrc = (const float*)d_in[1];
    const float* Wdst = (const float*)d_in[2];
    const float* a    = (const float*)d_in[3];

    float* ws      = (float*)d_ws;
    float* hsrc    = ws;                                   // 524288 f
    float* hdstNT  = hsrc + (size_t)B_ * H_ * N_ * U_;     // 524288 f
    float* Drow    = hdstNT + (size_t)B_ * H_ * U_ * N_;   // 16384 f
    float* ascaled = Drow + (size_t)B_ * H_ * N_;          // 128 f
    short* hsrcT   = (short*)(ascaled + H_ * U_);          // 524288 sh

    proj_kernel<<<(B_ * N_) / 8, 256, 0, stream>>>(x, Wsrc, Wdst, a,
                                                   hsrc, hdstNT, Drow, ascaled,
                                                   hsrcT);
    attn_kernel<<<B_ * H_ * (N_ / 16), 512, 0, stream>>>(hsrc, hdstNT, Drow,
                                                         ascaled, hsrcT,
                                                         (float*)d_out);
}

// Round 12
// 99.050 us; speedup vs baseline: 1.2838x; 1.1059x over previous
//
#include <hip/hip_runtime.h>
#include <hip/hip_bf16.h>

#define B_ 8
#define N_ 512
#define F_ 128
#define H_ 4
#define U_ 32
#define LEAKY_ALPHA 0.2f
#define PS 520     // pbf row stride (bf16 elems)

typedef __attribute__((ext_vector_type(8))) short short8;
typedef __attribute__((ext_vector_type(4))) short short4v;
typedef __attribute__((ext_vector_type(4))) float f32x4;

static __device__ __forceinline__ short f2bf_s(float x) {
    __hip_bfloat16 hv = __float2bfloat16(x);
    return *reinterpret_cast<short*>(&hv);
}
static __device__ __forceinline__ float bf2f_s(short v) {
    return __uint_as_float(((unsigned)(unsigned short)v) << 16);
}

// ---------------------------------------------------------------------------
// Kernel 1: projections. C=2 restructure: each thread computes BOTH src and
// dst for its (h,u) over 4 rows -> total broadcast ds_read_b128 count
// HALVES vs R9 (reads scale as 1/cols-per-thread; R9 was ~10 us LDS-bound).
// Block = 16 rows, 512 threads (u = t&31, h = (t>>5)&3, rq = t>>7 -> rows
// rq*4..rq*4+3). Grid = 256 = 1 block/CU, 2 waves/SIMD.
//   hsrc   = x@Wsrc (f32)           [bh][n][u]
//   hsrcT  = bf16(x@Wsrc)^T         [bh*32+u][n]  (MFMA B-frag layout)
//   hdstNT = -(x@Wdst) (f32)^T      [bh*32+u][j]  (coalesced per-lane d-rows)
//   Drow[j] = sum_u a_u d_ju ; ascaled = 0.8*a
// score(i,j) ~ D_j + sum_u (0.8 a_u) max(s_iu, -d_ju)  (0.2*A_i dropped;
// softmax shift-invariant).
// ---------------------------------------------------------------------------
__global__ __launch_bounds__(512) void proj_kernel(
    const float* __restrict__ x, const float* __restrict__ Wsrc,
    const float* __restrict__ Wdst, const float* __restrict__ a,
    float* __restrict__ hsrc, float* __restrict__ hdstNT,
    float* __restrict__ Drow, float* __restrict__ ascaled,
    short* __restrict__ hsrcT)
{
    __shared__ float4 xlds[16 * 32];              // 16 rows x 128 floats
    const int t  = threadIdx.x;
    const int r0 = blockIdx.x * 16;

    xlds[t] = ((const float4*)x)[(size_t)r0 * 32 + t];
    __syncthreads();

    const int u  = t & 31;
    const int h  = (t >> 5) & 3;
    const int rq = t >> 7;                        // 0..3 -> 4 rows each
    const float* Ws = Wsrc + h * (F_ * U_) + u;
    const float* Wd = Wdst + h * (F_ * U_) + u;

    float as[4], ad[4];
#pragma unroll
    for (int r = 0; r < 4; ++r) { as[r] = 0.f; ad[r] = 0.f; }

#pragma unroll 2
    for (int fc = 0; fc < 32; ++fc) {
        const float s0 = Ws[(4 * fc + 0) * U_];
        const float s1 = Ws[(4 * fc + 1) * U_];
        const float s2 = Ws[(4 * fc + 2) * U_];
        const float s3 = Ws[(4 * fc + 3) * U_];
        const float d0 = Wd[(4 * fc + 0) * U_];
        const float d1 = Wd[(4 * fc + 1) * U_];
        const float d2 = Wd[(4 * fc + 2) * U_];
        const float d3 = Wd[(4 * fc + 3) * U_];
#pragma unroll
        for (int r = 0; r < 4; ++r) {
            const float4 xv = xlds[(rq * 4 + r) * 32 + fc];
            float vs = as[r], vd = ad[r];
            vs = fmaf(xv.x, s0, vs);  vd = fmaf(xv.x, d0, vd);
            vs = fmaf(xv.y, s1, vs);  vd = fmaf(xv.y, d1, vd);
            vs = fmaf(xv.z, s2, vs);  vd = fmaf(xv.z, d2, vd);
            vs = fmaf(xv.w, s3, vs);  vd = fmaf(xv.w, d3, vd);
            as[r] = vs; ad[r] = vd;
        }
    }

    const float av = a[h * U_ + u];
    if (t < 128 && blockIdx.x == 0)
        ascaled[h * U_ + u] = (1.f - LEAKY_ALPHA) * av;

    const int b  = r0 >> 9;
    const int n0 = (r0 & (N_ - 1)) + rq * 4;
    const int bh = b * H_ + h;

    // hsrc (f32, [n][u]) + hsrcT (bf16^T)
    short4v pk;
#pragma unroll
    for (int r = 0; r < 4; ++r) {
        hsrc[((size_t)(bh * N_ + n0 + r) << 5) + u] = as[r];
        pk[r] = f2bf_s(as[r]);
    }
    *(short4v*)&hsrcT[((size_t)(bh * U_) + u) * N_ + n0] = pk;

    // hdstNT (negated, transposed, f32)
    float4 nv;
    nv.x = -ad[0]; nv.y = -ad[1]; nv.z = -ad[2]; nv.w = -ad[3];
    *(float4*)&hdstNT[((size_t)(bh * U_) + u) * N_ + n0] = nv;

    // Drow: reduce a_u*d over the 32 u-lanes of this wave-half
#pragma unroll
    for (int r = 0; r < 4; ++r) {
        float v = ad[r] * av;
        v += __shfl_xor(v, 1);
        v += __shfl_xor(v, 2);
        v += __shfl_xor(v, 4);
        v += __shfl_xor(v, 8);
        v += __shfl_xor(v, 16);
        if (u == 0) Drow[bh * N_ + n0 + r] = v;
    }
}

// ---------------------------------------------------------------------------
// Kernel 2: attention — R9's proven structure + ONE addition: a coalesced
// 2 KB warming load of the tile's s-rows issued before the d-loads, so the
// per-i uniform s fetches hit warm L2 (~200 cyc, hidden by 8 waves/SIMD)
// instead of cold L3/HBM (~600-900 cyc, the suspected 20 us stall).
// Block = 512 thr = 8 waves; lane = j owns one d-row (32 pinned scalars,
// coalesced from hdstNT). Phase A: zero LDS reads, zero shuffles.
// l via all-thread pbf reduce; Phase C: MFMA p @ srcT.
// Grid = 32 bh x 32 tiles(16 i) = 1024 blocks.
// ---------------------------------------------------------------------------
__global__ __launch_bounds__(512, 4) void attn_kernel(
    const float* __restrict__ hsrc, const float* __restrict__ hdstNT,
    const float* __restrict__ Drow, const float* __restrict__ ascaled,
    const short* __restrict__ hsrcT, float* __restrict__ out)
{
    __shared__ __align__(16) short pbf[16 * PS];  // 16.6 KB p bf16 [i][j]
    __shared__ f32x4 scr[8][64];                  // 8 KB K-partials
    __shared__ float lfin[16];                    // 1/l per i

    const int t    = threadIdx.x;
    const int L    = t & 63;
    const int w    = __builtin_amdgcn_readfirstlane(t >> 6);
    const int tile = blockIdx.x & 31;
    const int bh   = blockIdx.x >> 5;
    const int h    = bh & 3;
    const int b    = bh >> 2;
    const size_t bhN = (size_t)bh * N_;
    const int ig0  = tile * 16;
    const int j    = t;                           // lane owns column j

    const float* sB = hsrc + ((bhN + ig0) << 5);  // 16x32, block-uniform

    // ---- L2-warming prefetch of the tile's s-rows (2 KB, coalesced) ----
    {
        const float warm = sB[t];
        asm volatile("" :: "v"(warm));            // materialize, don't DCE
    }

    // ---- per-lane d-row (coalesced, pinned) ----
    const float* dT = hdstNT + ((size_t)bh * U_) * N_ + j;
#define DL(k) float d##k = dT[(k) * N_];
    DL(0) DL(1) DL(2) DL(3) DL(4) DL(5) DL(6) DL(7)
    DL(8) DL(9) DL(10) DL(11) DL(12) DL(13) DL(14) DL(15)
    DL(16) DL(17) DL(18) DL(19) DL(20) DL(21) DL(22) DL(23)
    DL(24) DL(25) DL(26) DL(27) DL(28) DL(29) DL(30) DL(31)
#undef DL
#define PIN4(a0,a1,a2,a3) asm volatile("" : "+v"(a0), "+v"(a1), "+v"(a2), "+v"(a3));
    PIN4(d0,d1,d2,d3)     PIN4(d4,d5,d6,d7)
    PIN4(d8,d9,d10,d11)   PIN4(d12,d13,d14,d15)
    PIN4(d16,d17,d18,d19) PIN4(d20,d21,d22,d23)
    PIN4(d24,d25,d26,d27) PIN4(d28,d29,d30,d31)
#undef PIN4

    const float Dj = Drow[bhN + j];
    const float* aS = ascaled + h * U_;           // block-uniform

#define TERM(k, dk, accv) accv = fmaf(aS[k], fmaxf(sR[k], dk), accv);
#pragma unroll 2
    for (int i = 0; i < 16; ++i) {
        const float* sR = sB + (i << 5);          // uniform -> s_load
        float acA = 0.f, acB = 0.f;
        TERM(0,  d0,  acA) TERM(1,  d1,  acB) TERM(2,  d2,  acA) TERM(3,  d3,  acB)
        TERM(4,  d4,  acA) TERM(5,  d5,  acB) TERM(6,  d6,  acA) TERM(7,  d7,  acB)
        TERM(8,  d8,  acA) TERM(9,  d9,  acB) TERM(10, d10, acA) TERM(11, d11, acB)
        TERM(12, d12, acA) TERM(13, d13, acB) TERM(14, d14, acA) TERM(15, d15, acB)
        TERM(16, d16, acA) TERM(17, d17, acB) TERM(18, d18, acA) TERM(19, d19, acB)
        TERM(20, d20, acA) TERM(21, d21, acB) TERM(22, d22, acA) TERM(23, d23, acB)
        TERM(24, d24, acA) TERM(25, d25, acB) TERM(26, d26, acA) TERM(27, d27, acB)
        TERM(28, d28, acA) TERM(29, d29, acB) TERM(30, d30, acA) TERM(31, d31, acB)
        const float e = __expf(Dj + acA + acB);
        pbf[i * PS + j] = f2bf_s(e);
    }
#undef TERM
    __syncthreads();

    // ---- l reduce: thread (ri = t>>5, rg = t&31) sums 16 j's of row ri ----
    {
        const int ri = t >> 5;
        const int rg = t & 31;
        const short8* pr = (const short8*)(pbf + ri * PS + rg * 16);
        const short8 pa = pr[0];
        const short8 pb = pr[1];
        float sum = 0.f;
#pragma unroll
        for (int k = 0; k < 8; ++k) sum += bf2f_s(pa[k]) + bf2f_s(pb[k]);
        sum += __shfl_xor(sum, 1);
        sum += __shfl_xor(sum, 2);
        sum += __shfl_xor(sum, 4);
        sum += __shfl_xor(sum, 8);
        sum += __shfl_xor(sum, 16);
        if (rg == 0) lfin[ri] = __builtin_amdgcn_rcpf(sum);
    }

    // ---- Phase C: MFMA  out = p @ src ; wave w = (nt = w&1, ks = w>>1) ----
    const int m  = L & 15;
    const int kq = L >> 4;
    const int nt = w & 1;
    const int ks = w >> 1;
    const short* Ap = pbf + m * PS + ks * 128 + kq * 8;
    const short* Bp = hsrcT + ((size_t)bh * U_ + nt * 16 + m) * N_ + ks * 128 + kq * 8;

    f32x4 acc = {0.f, 0.f, 0.f, 0.f};
#pragma unroll
    for (int st = 0; st < 4; ++st) {
        const short8 af = *(const short8*)(Ap + st * 32);
        const short8 bf = *(const short8*)(Bp + st * 32);
        acc = __builtin_amdgcn_mfma_f32_16x16x32_bf16(af, bf, acc, 0, 0, 0);
    }
    scr[w][L] = acc;
    __syncthreads();

    if (w < 2) {                               // wave w reduces ntile=w
        f32x4 s0 = scr[w][L];
        const f32x4 s1 = scr[w + 2][L];
        const f32x4 s2 = scr[w + 4][L];
        const f32x4 s3 = scr[w + 6][L];
        s0 += s1; s0 += s2; s0 += s3;
#pragma unroll
        for (int r = 0; r < 4; ++r) {
            const int il = kq * 4 + r;         // C/D: row=(lane>>4)*4+reg
            out[((size_t)(b * N_ + ig0 + il)) * (H_ * U_) + h * U_ + w * 16 + m]
                = s0[r] * lfin[il];
        }
    }
}

// ---------------------------------------------------------------------------
extern "C" void kernel_launch(void* const* d_in, const int* in_sizes, int n_in,
                              void* d_out, int out_size, void* d_ws, size_t ws_size,
                              hipStream_t stream) {
    const float* x    = (const float*)d_in[0];
    const float* Wsrc = (const float*)d_in[1];
    const float* Wdst = (const float*)d_in[2];
    const float* a    = (const float*)d_in[3];

    float* ws      = (float*)d_ws;
    float* hsrc    = ws;                                   // 524288 f
    float* hdstNT  = hsrc + (size_t)B_ * H_ * N_ * U_;     // 524288 f
    float* Drow    = hdstNT + (size_t)B_ * H_ * U_ * N_;   // 16384 f
    float* ascaled = Drow + (size_t)B_ * H_ * N_;          // 128 f
    short* hsrcT   = (short*)(ascaled + H_ * U_);          // 524288 sh

    proj_kernel<<<(B_ * N_) / 16, 512, 0, stream>>>(x, Wsrc, Wdst, a,
                                                    hsrc, hdstNT, Drow, ascaled,
                                                    hsrcT);
    attn_kernel<<<B_ * H_ * (N_ / 16), 512, 0, stream>>>(hsrc, hdstNT, Drow,
                                                         ascaled, hsrcT,
                                                         (float*)d_out);
}